// Round 1
// baseline (413.765 us; speedup 1.0000x reference)
//
#include <hip/hip_runtime.h>

#define NQ 23
#define DIM (1u<<NQ)
#define TILE_BITS 13
#define TILE (1<<TILE_BITS)    // 8192 complex per workgroup tile (64 KB LDS)
#define NTILES ((int)(DIM/TILE)) // 1024
#define THREADS 512

// ws layout:
//   [0, 16)        : double accum[2]  {norm2, signed_sum}
//   [64, 64+1472)  : float mats[2][23][8]  (fused 2x2 complex gate per layer/qubit)
//   [4096, 4096+64MB) : float2 bufB (intermediate state)

struct C2x2 { float ar,ai,br,bi,cr,ci,dr,di; };

// LDS bank-conflict swizzle: mix idx bits {7,8,9} into bank bits {1,2,3}.
// Keeps (even,odd) pairs adjacent so float2 accesses stay b64. Involution.
__device__ __forceinline__ int sw(int i) { return i ^ (((i>>7)&7)<<1); }

__device__ __forceinline__ C2x2 ldmat(const float* __restrict__ gm, int layer, int q){
  const float* p = gm + (layer*NQ + q)*8;
  C2x2 m;
  m.ar=p[0]; m.ai=p[1]; m.br=p[2]; m.bi=p[3];
  m.cr=p[4]; m.ci=p[5]; m.dr=p[6]; m.di=p[7];
  return m;
}

// (x,y) -> (m00 x + m01 y, m10 x + m11 y), complex
__device__ __forceinline__ void appair(float&xr,float&xi,float&yr,float&yi,const C2x2&m){
  float nxr = m.ar*xr - m.ai*xi + m.br*yr - m.bi*yi;
  float nxi = m.ar*xi + m.ai*xr + m.br*yi + m.bi*yr;
  float nyr = m.cr*xr - m.ci*xi + m.dr*yr - m.di*yi;
  float nyi = m.cr*xi + m.ci*xr + m.dr*yi + m.di*yr;
  xr=nxr; xi=nxi; yr=nyr; yi=nyi;
}

// deposit: spread t's 9 bits into the 13-bit tile index, leaving zeros at B0<B1<B2<B3
template<int B0,int B1,int B2,int B3>
__device__ __forceinline__ int depo(int t){
  int x=t;
  x = ((x & ~((1<<B0)-1))<<1) | (x & ((1<<B0)-1));
  x = ((x & ~((1<<B1)-1))<<1) | (x & ((1<<B1)-1));
  x = ((x & ~((1<<B2)-1))<<1) | (x & ((1<<B2)-1));
  x = ((x & ~((1<<B3)-1))<<1) | (x & ((1<<B3)-1));
  return x;
}

// In-place LDS round: each thread owns the 16-amp cube over tile-local bits B0..B3,
// applies gates q0..q3 (layer `layer`, -1 = skip) on the respective bit.
template<int B0,int B1,int B2,int B3>
__device__ __forceinline__ void lds_round(float2* lds, const float* __restrict__ gm,
                                          int layer, int q0,int q1,int q2,int q3, int tid){
  int base = depo<B0,B1,B2,B3>(tid);
  float vr[16], vi[16];
  int addr[16];
  #pragma unroll
  for(int k=0;k<16;++k){
    int idx = base | ((k&1)<<B0) | (((k>>1)&1)<<B1) | (((k>>2)&1)<<B2) | (((k>>3)&1)<<B3);
    addr[k]=sw(idx);
    float2 v = lds[addr[k]];
    vr[k]=v.x; vi[k]=v.y;
  }
  if(q0>=0){ C2x2 m=ldmat(gm,layer,q0);
    #pragma unroll
    for(int k=0;k<16;++k) if(!(k&1)) appair(vr[k],vi[k],vr[k+1],vi[k+1],m); }
  if(q1>=0){ C2x2 m=ldmat(gm,layer,q1);
    #pragma unroll
    for(int k=0;k<16;++k) if(!(k&2)) appair(vr[k],vi[k],vr[k+2],vi[k+2],m); }
  if(q2>=0){ C2x2 m=ldmat(gm,layer,q2);
    #pragma unroll
    for(int k=0;k<16;++k) if(!(k&4)) appair(vr[k],vi[k],vr[k+4],vi[k+4],m); }
  if(q3>=0){ C2x2 m=ldmat(gm,layer,q3);
    #pragma unroll
    for(int k=0;k<8;++k) appair(vr[k],vi[k],vr[k+8],vi[k+8],m); }
  #pragma unroll
  for(int k=0;k<16;++k) lds[addr[k]] = make_float2(vr[k],vi[k]);
}

// init: fuse rotation pairs into 2x2 complex matrices; zero accumulators.
__global__ void initk(const float* __restrict__ thetas, float* __restrict__ gm,
                      double* __restrict__ accum){
  int t = threadIdx.x;
  if(t<2) accum[t]=0.0;
  if(t<46){
    int layer = t/NQ, q = t - layer*NQ;
    double a = 0.5*(double)thetas[layer*2*NQ + q*2 + 0];
    double b = 0.5*(double)thetas[layer*2*NQ + q*2 + 1];
    double ca=cos(a), sa=sin(a), cb=cos(b), sb=sin(b);
    float* p = gm + t*8;
    if(layer==0){ // U = RZ(b)*RY(a)
      p[0]=(float)( ca*cb); p[1]=(float)(-ca*sb);
      p[2]=(float)(-sa*cb); p[3]=(float)( sa*sb);
      p[4]=(float)( sa*cb); p[5]=(float)( sa*sb);
      p[6]=(float)( ca*cb); p[7]=(float)( ca*sb);
    } else {      // U = RY(b)*RX(a)
      p[0]=(float)( cb*ca); p[1]=(float)( sb*sa);
      p[2]=(float)(-sb*ca); p[3]=(float)(-cb*sa);
      p[4]=(float)( sb*ca); p[5]=(float)(-cb*sa);
      p[6]=(float)( cb*ca); p[7]=(float)(-sb*sa);
    }
  }
}

// Pass A: strided tile (global bits {0,1,2} x {13..22}); layer-0 gates on
// qubits {22,21,20} (in registers at load) and {9..0} (LDS rounds).
// In-place on sr/si. Accumulates norm^2 of the ORIGINAL state.
__global__ __launch_bounds__(THREADS,4)
void passA(float* __restrict__ sr, float* __restrict__ si,
           const float* __restrict__ gm, double* __restrict__ accum){
  __shared__ float2 lds[TILE];
  int tid = threadIdx.x;
  int b = blockIdx.x;
  int T = ((b&7)<<7) | (b>>3);  // consecutive T land on same XCD (blockIdx%8 RR)
  double nrm = 0.0;
  C2x2 m22 = ldmat(gm,0,22), m21 = ldmat(gm,0,21), m20 = ldmat(gm,0,20);
  #pragma unroll
  for(int c=0;c<2;++c){
    int hi = tid + c*THREADS;
    int g = (hi<<TILE_BITS) + (T<<3);
    float4 r0 = *(const float4*)(sr+g);
    float4 r1 = *(const float4*)(sr+g+4);
    float4 i0 = *(const float4*)(si+g);
    float4 i1 = *(const float4*)(si+g+4);
    float vr[8] = {r0.x,r0.y,r0.z,r0.w,r1.x,r1.y,r1.z,r1.w};
    float vi[8] = {i0.x,i0.y,i0.z,i0.w,i1.x,i1.y,i1.z,i1.w};
    #pragma unroll
    for(int k=0;k<8;++k) nrm += (double)vr[k]*vr[k] + (double)vi[k]*vi[k];
    #pragma unroll
    for(int k=0;k<8;++k) if(!(k&1)) appair(vr[k],vi[k],vr[k+1],vi[k+1],m22);
    #pragma unroll
    for(int k=0;k<8;++k) if(!(k&2)) appair(vr[k],vi[k],vr[k+2],vi[k+2],m21);
    #pragma unroll
    for(int k=0;k<4;++k) appair(vr[k],vi[k],vr[k+4],vi[k+4],m20);
    int lb = hi<<3;
    #pragma unroll
    for(int k=0;k<8;++k) lds[sw(lb+k)] = make_float2(vr[k],vi[k]);
  }
  #pragma unroll
  for(int off=32;off>0;off>>=1) nrm += __shfl_down(nrm, off);
  if((tid&63)==0) atomicAdd(accum+0, nrm);
  __syncthreads();
  lds_round<3,4,5,6>  (lds, gm, 0, 9,8,7,6, tid);   // global bits 13..16
  __syncthreads();
  lds_round<7,8,9,10> (lds, gm, 0, 5,4,3,2, tid);   // global bits 17..20
  __syncthreads();
  lds_round<5,6,11,12>(lds, gm, 0, -1,-1,1,0, tid); // global bits 21,22
  __syncthreads();
  #pragma unroll
  for(int c=0;c<2;++c){
    int hi = tid + c*THREADS;
    int g = (hi<<TILE_BITS) + (T<<3);
    int lb = hi<<3;
    float vr[8], vi[8];
    #pragma unroll
    for(int k=0;k<8;++k){ float2 v = lds[sw(lb+k)]; vr[k]=v.x; vi[k]=v.y; }
    *(float4*)(sr+g)   = make_float4(vr[0],vr[1],vr[2],vr[3]);
    *(float4*)(sr+g+4) = make_float4(vr[4],vr[5],vr[6],vr[7]);
    *(float4*)(si+g)   = make_float4(vi[0],vi[1],vi[2],vi[3]);
    *(float4*)(si+g+4) = make_float4(vi[4],vi[5],vi[6],vi[7]);
  }
}

// Pass B: contiguous low-13 tile. Layer-0 gates on qubits 19..10 (input space),
// Gray permutation (input tile = Gray(T)-aligned block, in-LDS local perm),
// layer-1 gates on qubits 22..10 (output space). Writes interleaved float2.
__global__ __launch_bounds__(THREADS,4)
void passB(const float* __restrict__ sr, const float* __restrict__ si,
           float2* __restrict__ outb, const float* __restrict__ gm){
  __shared__ float2 lds[TILE];
  int tid = threadIdx.x;
  int T = blockIdx.x;
  int in_base = (T ^ (T>>1)) << TILE_BITS; // Gray image of aligned output block
  int cT = (T&1) << 12;
  {
    int jb = tid<<4;
    const float4* sr4 = (const float4*)(sr + in_base + jb);
    const float4* si4 = (const float4*)(si + in_base + jb);
    #pragma unroll
    for(int i=0;i<4;++i){
      float4 r = sr4[i], m = si4[i];
      lds[sw(jb+4*i+0)] = make_float2(r.x, m.x);
      lds[sw(jb+4*i+1)] = make_float2(r.y, m.y);
      lds[sw(jb+4*i+2)] = make_float2(r.z, m.z);
      lds[sw(jb+4*i+3)] = make_float2(r.w, m.w);
    }
  }
  __syncthreads();
  lds_round<3,4,5,6>  (lds, gm, 0, 19,18,17,16, tid);
  __syncthreads();
  lds_round<7,8,9,10> (lds, gm, 0, 15,14,13,12, tid);
  __syncthreads();
  lds_round<5,6,11,12>(lds, gm, 0, -1,-1,11,10, tid);
  __syncthreads();
  { // Gray perm (local: j = (i ^ (i>>1)) ^ cT) fused with layer-1 qubits 22..19
    int ib = tid<<4;
    int jbase = ((tid<<4) ^ (tid<<3)) ^ cT;
    float vr[16], vi[16];
    #pragma unroll
    for(int k=0;k<16;++k){
      int j = jbase ^ (k ^ (k>>1));
      float2 v = lds[sw(j)];
      vr[k]=v.x; vi[k]=v.y;
    }
    __syncthreads(); // all reads done before any writes
    C2x2 g0 = ldmat(gm,1,22);
    #pragma unroll
    for(int k=0;k<16;++k) if(!(k&1)) appair(vr[k],vi[k],vr[k+1],vi[k+1],g0);
    C2x2 g1 = ldmat(gm,1,21);
    #pragma unroll
    for(int k=0;k<16;++k) if(!(k&2)) appair(vr[k],vi[k],vr[k+2],vi[k+2],g1);
    C2x2 g2 = ldmat(gm,1,20);
    #pragma unroll
    for(int k=0;k<16;++k) if(!(k&4)) appair(vr[k],vi[k],vr[k+4],vi[k+4],g2);
    C2x2 g3 = ldmat(gm,1,19);
    #pragma unroll
    for(int k=0;k<8;++k) appair(vr[k],vi[k],vr[k+8],vi[k+8],g3);
    #pragma unroll
    for(int k=0;k<16;++k) lds[sw(ib+k)] = make_float2(vr[k],vi[k]);
  }
  __syncthreads();
  lds_round<4,5,6,7>  (lds, gm, 1, 18,17,16,15, tid);
  __syncthreads();
  lds_round<8,9,10,11>(lds, gm, 1, 14,13,12,11, tid);
  __syncthreads();
  { // final: cube (0,1,2,12) -> apply layer-1 qubit 10, write out two 64B chunks
    int base = tid<<3; // bits 3..11
    float vr[16], vi[16];
    #pragma unroll
    for(int k=0;k<16;++k){
      int idx = (base | (k&7)) | ((k>>3)<<12);
      float2 v = lds[sw(idx)]; vr[k]=v.x; vi[k]=v.y;
    }
    C2x2 m10 = ldmat(gm,1,10);
    #pragma unroll
    for(int k=0;k<8;++k) appair(vr[k],vi[k],vr[k+8],vi[k+8],m10);
    int ob = (T<<TILE_BITS) + base;
    float4* o0 = (float4*)(outb + ob);
    float4* o1 = (float4*)(outb + ob + 4096);
    o0[0]=make_float4(vr[0],vi[0],vr[1],vi[1]);
    o0[1]=make_float4(vr[2],vi[2],vr[3],vi[3]);
    o0[2]=make_float4(vr[4],vi[4],vr[5],vi[5]);
    o0[3]=make_float4(vr[6],vi[6],vr[7],vi[7]);
    o1[0]=make_float4(vr[8],vi[8],vr[9],vi[9]);
    o1[1]=make_float4(vr[10],vi[10],vr[11],vi[11]);
    o1[2]=make_float4(vr[12],vi[12],vr[13],vi[13]);
    o1[3]=make_float4(vr[14],vi[14],vr[15],vi[15]);
  }
}

// Pass C: strided tile; layer-1 gates qubits 9..0; signed |amp|^2 reduce.
// (Final CNOT ladder preserves bit 22, so it is dropped entirely.)
__global__ __launch_bounds__(THREADS,4)
void passC(const float2* __restrict__ inb, const float* __restrict__ gm,
           double* __restrict__ accum){
  __shared__ float2 lds[TILE];
  int tid = threadIdx.x;
  int b = blockIdx.x;
  int T = ((b&7)<<7) | (b>>3);
  #pragma unroll
  for(int c=0;c<2;++c){
    int hi = tid + c*THREADS;
    int g = (hi<<TILE_BITS) + (T<<3);
    const float4* p = (const float4*)(inb + g);
    int lb = hi<<3;
    #pragma unroll
    for(int i=0;i<4;++i){
      float4 v = p[i];
      lds[sw(lb+2*i)]   = make_float2(v.x,v.y);
      lds[sw(lb+2*i+1)] = make_float2(v.z,v.w);
    }
  }
  __syncthreads();
  lds_round<3,4,5,6>  (lds, gm, 1, 9,8,7,6, tid); // global bits 13..16
  __syncthreads();
  lds_round<7,8,9,10> (lds, gm, 1, 5,4,3,2, tid); // global bits 17..20
  __syncthreads();
  double s = 0.0;
  { // final cube (5,6,11,12): gates qubits 1 (bit21), 0 (bit22) + signed reduce
    int base = depo<5,6,11,12>(tid);
    float vr[16], vi[16];
    #pragma unroll
    for(int k=0;k<16;++k){
      int idx = base | ((k&1)<<5) | (((k>>1)&1)<<6) | (((k>>2)&1)<<11) | (((k>>3)&1)<<12);
      float2 v = lds[sw(idx)]; vr[k]=v.x; vi[k]=v.y;
    }
    C2x2 m1=ldmat(gm,1,1), m0=ldmat(gm,1,0);
    #pragma unroll
    for(int k=0;k<16;++k) if(!(k&4)) appair(vr[k],vi[k],vr[k+4],vi[k+4],m1);
    #pragma unroll
    for(int k=0;k<8;++k) appair(vr[k],vi[k],vr[k+8],vi[k+8],m0);
    #pragma unroll
    for(int k=0;k<16;++k){
      double p2 = (double)vr[k]*vr[k] + (double)vi[k]*vi[k];
      s += (k&8) ? -p2 : p2; // bit12 local = global bit 22 (qubit 0): -1 eigenvalue
    }
  }
  #pragma unroll
  for(int off=32;off>0;off>>=1) s += __shfl_down(s, off);
  if((tid&63)==0) atomicAdd(accum+1, s);
}

__global__ void fink(const double* __restrict__ accum, float* __restrict__ out){
  out[0] = (float)(accum[1]/accum[0]);
}

extern "C" void kernel_launch(void* const* d_in, const int* in_sizes, int n_in,
                              void* d_out, int out_size, void* d_ws, size_t ws_size,
                              hipStream_t stream){
  (void)in_sizes; (void)n_in; (void)out_size; (void)ws_size;
  const float* thetas = (const float*)d_in[0];
  float* sr = (float*)d_in[1];   // mutated in place; harness restores before each launch
  float* si = (float*)d_in[2];
  char* ws = (char*)d_ws;
  double* accum = (double*)ws;
  float* gm = (float*)(ws + 64);
  float2* bufB = (float2*)(ws + 4096);

  initk<<<1, 64, 0, stream>>>(thetas, gm, accum);
  passA<<<NTILES, THREADS, 0, stream>>>(sr, si, gm, accum);
  passB<<<NTILES, THREADS, 0, stream>>>(sr, si, bufB, gm);
  passC<<<NTILES, THREADS, 0, stream>>>(bufB, gm, accum);
  fink<<<1, 1, 0, stream>>>(accum, (float*)d_out);
}

// Round 2
// 340.639 us; speedup vs baseline: 1.2147x; 1.2147x over previous
//
#include <hip/hip_runtime.h>

#define NQ 23
#define DIM (1u<<NQ)
#define TILE_BITS 13
#define TILE (1<<TILE_BITS)      // 8192 complex per LDS tile (64 KB)
#define THREADS 512

// ws layout:
//   [0, 16)       : double accum[2]  {norm2, signed_sum}
//   [64, 64+1472) : float mats[2][23][8]
//
// Math: E = <psi''| Z_22 |psi''> with psi'' = Ladder2 . L1 . Gray . L0 . psi.
// Ladder2 preserves bit22 -> dropped. L1 = U1(bit22) (x) V, V cancels in the
// expectation -> only U1 on qubit 0 survives. So:
//   passA: L0 gates qubits 0..9 (bits 22..13); qubit0 via register butterfly.
//   passB: L0 gates qubits 10..22 (bits 12..0), Gray gather, U1 pair across
//          bit22, signed |.|^2 + norm^2 reduce. No intermediate buffer.

struct C2x2 { float ar,ai,br,bi,cr,ci,dr,di; };

// LDS swizzle: mix idx bits {7,8,9} into bank bits {1,2,3}; keeps float2 b64.
__device__ __forceinline__ int sw(int i) { return i ^ (((i>>7)&7)<<1); }

__device__ __forceinline__ C2x2 ldmat(const float* __restrict__ gm, int layer, int q){
  const float* p = gm + (layer*NQ + q)*8;
  C2x2 m;
  m.ar=p[0]; m.ai=p[1]; m.br=p[2]; m.bi=p[3];
  m.cr=p[4]; m.ci=p[5]; m.dr=p[6]; m.di=p[7];
  return m;
}

__device__ __forceinline__ void appair(float&xr,float&xi,float&yr,float&yi,const C2x2&m){
  float nxr = m.ar*xr - m.ai*xi + m.br*yr - m.bi*yi;
  float nxi = m.ar*xi + m.ai*xr + m.br*yi + m.bi*yr;
  float nyr = m.cr*xr - m.ci*xi + m.dr*yr - m.di*yi;
  float nyi = m.cr*xi + m.ci*xr + m.dr*yi + m.di*yr;
  xr=nxr; xi=nxi; yr=nyr; yi=nyi;
}

__device__ __forceinline__ void ld16(const float* __restrict__ p, float* v){
  const float4* q = (const float4*)p;
  #pragma unroll
  for(int i=0;i<4;++i){ float4 t=q[i]; v[4*i]=t.x; v[4*i+1]=t.y; v[4*i+2]=t.z; v[4*i+3]=t.w; }
}
__device__ __forceinline__ void st16(float* __restrict__ p, const float* v){
  float4* q = (float4*)p;
  #pragma unroll
  for(int i=0;i<4;++i) q[i] = make_float4(v[4*i],v[4*i+1],v[4*i+2],v[4*i+3]);
}

template<int B0,int B1,int B2,int B3>
__device__ __forceinline__ int depo(int t){
  int x=t;
  x = ((x & ~((1<<B0)-1))<<1) | (x & ((1<<B0)-1));
  x = ((x & ~((1<<B1)-1))<<1) | (x & ((1<<B1)-1));
  x = ((x & ~((1<<B2)-1))<<1) | (x & ((1<<B2)-1));
  x = ((x & ~((1<<B3)-1))<<1) | (x & ((1<<B3)-1));
  return x;
}

// In-place LDS round over thread-owned 16-amp cube on local bits B0..B3;
// applies layer-`layer` gates q0..q3 (-1 = no gate) on those bits.
template<int B0,int B1,int B2,int B3>
__device__ __forceinline__ void lds_round(float2* lds, const float* __restrict__ gm,
                                          int layer, int q0,int q1,int q2,int q3, int tid){
  int base = depo<B0,B1,B2,B3>(tid);
  float vr[16], vi[16];
  int addr[16];
  #pragma unroll
  for(int k=0;k<16;++k){
    int idx = base | ((k&1)<<B0) | (((k>>1)&1)<<B1) | (((k>>2)&1)<<B2) | (((k>>3)&1)<<B3);
    addr[k]=sw(idx);
    float2 v = lds[addr[k]];
    vr[k]=v.x; vi[k]=v.y;
  }
  if(q0>=0){ C2x2 m=ldmat(gm,layer,q0);
    #pragma unroll
    for(int k=0;k<16;++k) if(!(k&1)) appair(vr[k],vi[k],vr[k+1],vi[k+1],m); }
  if(q1>=0){ C2x2 m=ldmat(gm,layer,q1);
    #pragma unroll
    for(int k=0;k<16;++k) if(!(k&2)) appair(vr[k],vi[k],vr[k+2],vi[k+2],m); }
  if(q2>=0){ C2x2 m=ldmat(gm,layer,q2);
    #pragma unroll
    for(int k=0;k<16;++k) if(!(k&4)) appair(vr[k],vi[k],vr[k+4],vi[k+4],m); }
  if(q3>=0){ C2x2 m=ldmat(gm,layer,q3);
    #pragma unroll
    for(int k=0;k<8;++k) appair(vr[k],vi[k],vr[k+8],vi[k+8],m); }
  #pragma unroll
  for(int k=0;k<16;++k) lds[addr[k]] = make_float2(vr[k],vi[k]);
}

__global__ void initk(const float* __restrict__ thetas, float* __restrict__ gm,
                      double* __restrict__ accum){
  int t = threadIdx.x;
  if(t<2) accum[t]=0.0;
  if(t<46){
    int layer = t/NQ, q = t - layer*NQ;
    double a = 0.5*(double)thetas[layer*2*NQ + q*2 + 0];
    double b = 0.5*(double)thetas[layer*2*NQ + q*2 + 1];
    double ca=cos(a), sa=sin(a), cb=cos(b), sb=sin(b);
    float* p = gm + t*8;
    if(layer==0){ // U = RZ(b)*RY(a)
      p[0]=(float)( ca*cb); p[1]=(float)(-ca*sb);
      p[2]=(float)(-sa*cb); p[3]=(float)( sa*sb);
      p[4]=(float)( sa*cb); p[5]=(float)( sa*sb);
      p[6]=(float)( ca*cb); p[7]=(float)( ca*sb);
    } else {      // U = RY(b)*RX(a)
      p[0]=(float)( cb*ca); p[1]=(float)( sb*sa);
      p[2]=(float)(-sb*ca); p[3]=(float)(-cb*sa);
      p[4]=(float)( sb*ca); p[5]=(float)(-cb*sa);
      p[6]=(float)( cb*ca); p[7]=(float)(-sb*sa);
    }
  }
}

// Pass A: window = addr bits {0..3} (64B rows) x {13..21}; bit 22 handled as a
// register butterfly across two sequential 8192-amp chunks. In-place.
// Applies layer-0 qubits 0..9.
__global__ __launch_bounds__(THREADS,4)
void passA(float* __restrict__ sr, float* __restrict__ si,
           const float* __restrict__ gm){
  __shared__ float2 lds[TILE];
  int tid = threadIdx.x;
  int b = blockIdx.x;
  // tile T = addr bits 4..12; keep T,T+1 on the same XCD (b%8 round-robin)
  int T = ((b&7)<<6) | (b>>3);
  int base = (tid<<TILE_BITS) | (T<<4);
  float vr0[16], vi0[16], vr1[16], vi1[16];
  ld16(sr+base, vr0);              ld16(si+base, vi0);
  ld16(sr+base+(1<<22), vr1);      ld16(si+base+(1<<22), vi1);
  C2x2 m0 = ldmat(gm,0,0);         // qubit 0 = bit 22
  #pragma unroll
  for(int k=0;k<16;++k) appair(vr0[k],vi0[k],vr1[k],vi1[k],m0);
  int lb = tid<<4;
  #pragma unroll
  for(int k=0;k<16;++k) lds[sw(lb|k)] = make_float2(vr0[k],vi0[k]);
  __syncthreads();
  lds_round<4,5,6,7>  (lds, gm, 0, 9,8,7,6, tid);  __syncthreads();
  lds_round<8,9,10,11>(lds, gm, 0, 5,4,3,2, tid);  __syncthreads();
  lds_round<0,1,2,12> (lds, gm, 0, -1,-1,-1,1, tid); __syncthreads();
  #pragma unroll
  for(int k=0;k<16;++k){ float2 v = lds[sw(lb|k)]; vr0[k]=v.x; vi0[k]=v.y; }
  st16(sr+base, vr0); st16(si+base, vi0);
  __syncthreads();                 // all LDS reads done before chunk1 writes
  #pragma unroll
  for(int k=0;k<16;++k) lds[sw(lb|k)] = make_float2(vr1[k],vi1[k]);
  __syncthreads();
  lds_round<4,5,6,7>  (lds, gm, 0, 9,8,7,6, tid);  __syncthreads();
  lds_round<8,9,10,11>(lds, gm, 0, 5,4,3,2, tid);  __syncthreads();
  lds_round<0,1,2,12> (lds, gm, 0, -1,-1,-1,1, tid); __syncthreads();
  #pragma unroll
  for(int k=0;k<16;++k){ float2 v = lds[sw(lb|k)]; vr1[k]=v.x; vi1[k]=v.y; }
  st16(sr+base+(1<<22), vr1); st16(si+base+(1<<22), vi1);
}

// Pass B: contiguous tiles. Per block: output tiles J and J+512 (bit-22 pair).
// chunk input tile = gray10(outTile); local Gray gather; layer-0 qubits 10..22;
// then U1 (layer-1 qubit 0) on the pair + signed |.|^2 and norm^2 reduction.
__global__ __launch_bounds__(THREADS,4)
void passB(const float* __restrict__ sr, const float* __restrict__ si,
           const float* __restrict__ gm, double* __restrict__ accum){
  __shared__ float2 lds[TILE];
  int tid = threadIdx.x;
  int J = blockIdx.x;                  // 512 blocks; pair (J, J+512)
  int gJ = J ^ (J>>1);                 // input tile of chunk0; chunk1 = gJ^768
  int cT = (J&1)<<12;                  // same for J and J+512
  int jbase = ((tid<<4) ^ (tid<<3)) ^ cT;
  C2x2 q22=ldmat(gm,0,22), q21=ldmat(gm,0,21), q20=ldmat(gm,0,20), q19=ldmat(gm,0,19);
  C2x2 u1 = ldmat(gm,1,0);
  float wr[16], wi[16];
  double ss=0.0, nn=0.0;
  int lb = tid<<4;
  #pragma unroll 1
  for(int c=0;c<2;++c){
    int in_base = ((c ? (gJ^768) : gJ) << TILE_BITS) + lb;
    float vr[16], vi[16];
    ld16(sr+in_base, vr); ld16(si+in_base, vi);
    // layer-0 gates on local bits 0..3 = qubits 22,21,20,19 (in registers)
    #pragma unroll
    for(int k=0;k<16;++k) if(!(k&1)) appair(vr[k],vi[k],vr[k+1],vi[k+1],q22);
    #pragma unroll
    for(int k=0;k<16;++k) if(!(k&2)) appair(vr[k],vi[k],vr[k+2],vi[k+2],q21);
    #pragma unroll
    for(int k=0;k<16;++k) if(!(k&4)) appair(vr[k],vi[k],vr[k+4],vi[k+4],q20);
    #pragma unroll
    for(int k=0;k<8;++k) appair(vr[k],vi[k],vr[k+8],vi[k+8],q19);
    #pragma unroll
    for(int k=0;k<16;++k) lds[sw(lb|k)] = make_float2(vr[k],vi[k]);
    __syncthreads();
    lds_round<4,5,6,7>  (lds, gm, 0, 18,17,16,15, tid); __syncthreads();
    lds_round<8,9,10,11>(lds, gm, 0, 14,13,12,11, tid); __syncthreads();
    lds_round<3,4,5,12> (lds, gm, 0, -1,-1,-1,10, tid); __syncthreads();
    if(c==0){
      #pragma unroll
      for(int k=0;k<16;++k){
        int j = jbase ^ (k ^ (k>>1));
        float2 v = lds[sw(j)]; wr[k]=v.x; wi[k]=v.y;
      }
      __syncthreads();                 // gather reads done before chunk1 writes
    } else {
      #pragma unroll
      for(int k=0;k<16;++k){
        int j = jbase ^ (k ^ (k>>1));
        float2 v = lds[sw(j)];
        float xr=v.x, xi=v.y;
        appair(wr[k],wi[k],xr,xi,u1);  // wr/wi = bit22=0 side, x = bit22=1 side
        double p0 = (double)wr[k]*wr[k] + (double)wi[k]*wi[k];
        double p1 = (double)xr*xr + (double)xi*xi;
        ss += p0 - p1;
        nn += p0 + p1;
      }
    }
  }
  #pragma unroll
  for(int off=32; off>0; off>>=1){ ss += __shfl_down(ss,off); nn += __shfl_down(nn,off); }
  if((tid&63)==0){ atomicAdd(accum+1, ss); atomicAdd(accum+0, nn); }
}

__global__ void fink(const double* __restrict__ accum, float* __restrict__ out){
  out[0] = (float)(accum[1]/accum[0]);
}

extern "C" void kernel_launch(void* const* d_in, const int* in_sizes, int n_in,
                              void* d_out, int out_size, void* d_ws, size_t ws_size,
                              hipStream_t stream){
  (void)in_sizes; (void)n_in; (void)out_size; (void)ws_size;
  const float* thetas = (const float*)d_in[0];
  float* sr = (float*)d_in[1];   // mutated in place; harness restores before each launch
  float* si = (float*)d_in[2];
  char* ws = (char*)d_ws;
  double* accum = (double*)ws;
  float* gm = (float*)(ws + 64);

  initk<<<1, 64, 0, stream>>>(thetas, gm, accum);
  passA<<<512, THREADS, 0, stream>>>(sr, si, gm);
  passB<<<512, THREADS, 0, stream>>>(sr, si, gm, accum);
  fink<<<1, 1, 0, stream>>>(accum, (float*)d_out);
}

// Round 3
// 306.818 us; speedup vs baseline: 1.3486x; 1.1102x over previous
//
#include <hip/hip_runtime.h>

#define NQ 23
#define TILE_BITS 13
#define TILE (1<<TILE_BITS)      // 8192 complex per LDS tile (64 KB)
#define THREADS 512
#define HALF (1u<<22)

// ws layout:
//   [0,16)          : double accum[2] {norm2, signed_sum}
//   [64, 64+1488)   : float gm: mats[2][23][8], then O-consts {a, O01r, O01i} at [368..370]
//   [4096, +33.6MB) : float2 stash (passA chunk1 rows; reused as passB w-tile stash)
//
// Math: E = <psi''| Z_22 |psi''>, psi'' = Ladder2 . L1 . Gray . L0 . psi.
// Ladder2 preserves bit22 -> dropped. Of L1 only qubit-0's U1 survives
// (rest cancels in the expectation), folded into M = U1^dag Z U1 (2x2 Hermitian).
//   passA: L0 qubits 0..9 (bits 22..13). q0 = register butterfly at load;
//          partner chunk self-spilled via ws (L2-hot). Norm^2 accumulated here.
//   passB: L0 qubits 10..22 (bits 12..0), Gray gather, M-form reduce across
//          output-tile pair (J, J+512) with w stash via ws.

struct C2x2 { float ar,ai,br,bi,cr,ci,dr,di; };

// LDS swizzle: XOR a hash of bits 4..11 into bank bits 0..3 (float2-granular).
// Puts every access pattern in this file at the b64 4-lane/bank-pair floor.
__device__ __forceinline__ int sw(int i){ return i ^ (((i>>4)^(i>>8)) & 15); }

__device__ __forceinline__ C2x2 ldmat(const float* __restrict__ gm, int layer, int q){
  const float* p = gm + (layer*NQ + q)*8;
  C2x2 m = {p[0],p[1],p[2],p[3],p[4],p[5],p[6],p[7]};
  return m;
}

__device__ __forceinline__ void appair(float&xr,float&xi,float&yr,float&yi,const C2x2&m){
  float nxr = m.ar*xr - m.ai*xi + m.br*yr - m.bi*yi;
  float nxi = m.ar*xi + m.ai*xr + m.br*yi + m.bi*yr;
  float nyr = m.cr*xr - m.ci*xi + m.dr*yr - m.di*yi;
  float nyi = m.cr*xi + m.ci*xr + m.dr*yi + m.di*yr;
  xr=nxr; xi=nxi; yr=nyr; yi=nyi;
}

__device__ __forceinline__ void ld8(const float* __restrict__ p, float* v){
  const float4* q = (const float4*)p;
  float4 a=q[0], b=q[1];
  v[0]=a.x; v[1]=a.y; v[2]=a.z; v[3]=a.w; v[4]=b.x; v[5]=b.y; v[6]=b.z; v[7]=b.w;
}
__device__ __forceinline__ void ld16(const float* __restrict__ p, float* v){
  const float4* q = (const float4*)p;
  #pragma unroll
  for(int i=0;i<4;++i){ float4 t=q[i]; v[4*i]=t.x; v[4*i+1]=t.y; v[4*i+2]=t.z; v[4*i+3]=t.w; }
}
__device__ __forceinline__ void st16(float* __restrict__ p, const float* v){
  float4* q = (float4*)p;
  #pragma unroll
  for(int i=0;i<4;++i) q[i] = make_float4(v[4*i],v[4*i+1],v[4*i+2],v[4*i+3]);
}

template<int B0,int B1,int B2>
__device__ __forceinline__ int depo3(int t){
  int x=t;
  x = ((x & ~((1<<B0)-1))<<1) | (x & ((1<<B0)-1));
  x = ((x & ~((1<<B1)-1))<<1) | (x & ((1<<B1)-1));
  x = ((x & ~((1<<B2)-1))<<1) | (x & ((1<<B2)-1));
  return x;
}

// One in-place LDS round: 3 gates on tile-local bits B0,B1,B2 (8-amp cubes,
// 2 cubes per thread). Caller provides barriers between rounds.
template<int B0,int B1,int B2>
__device__ __forceinline__ void round3(float2* lds, const C2x2&m0, const C2x2&m1,
                                       const C2x2&m2, int tid){
  #pragma unroll 1
  for(int c2=0;c2<2;++c2){
    int base = depo3<B0,B1,B2>(tid + 512*c2);
    float vr[8], vi[8];
    #pragma unroll
    for(int k=0;k<8;++k){
      int idx = base | ((k&1)<<B0) | (((k>>1)&1)<<B1) | (((k>>2)&1)<<B2);
      float2 v = lds[sw(idx)]; vr[k]=v.x; vi[k]=v.y;
    }
    #pragma unroll
    for(int k=0;k<8;++k) if(!(k&1)) appair(vr[k],vi[k],vr[k+1],vi[k+1],m0);
    #pragma unroll
    for(int k=0;k<8;++k) if(!(k&2)) appair(vr[k],vi[k],vr[k+2],vi[k+2],m1);
    #pragma unroll
    for(int k=0;k<4;++k) appair(vr[k],vi[k],vr[k+4],vi[k+4],m2);
    #pragma unroll
    for(int k=0;k<8;++k){
      int idx = base | ((k&1)<<B0) | (((k>>1)&1)<<B1) | (((k>>2)&1)<<B2);
      lds[sw(idx)] = make_float2(vr[k],vi[k]);
    }
  }
}

__global__ void initk(const float* __restrict__ thetas, float* __restrict__ gm,
                      double* __restrict__ accum){
  int t = threadIdx.x;
  if(t<2) accum[t]=0.0;
  if(t<46){
    int layer = t/NQ, q = t - layer*NQ;
    double a = 0.5*(double)thetas[layer*2*NQ + q*2 + 0];
    double b = 0.5*(double)thetas[layer*2*NQ + q*2 + 1];
    double ca=cos(a), sa=sin(a), cb=cos(b), sb=sin(b);
    float* p = gm + t*8;
    if(layer==0){ // U = RZ(b)*RY(a)
      p[0]=(float)( ca*cb); p[1]=(float)(-ca*sb);
      p[2]=(float)(-sa*cb); p[3]=(float)( sa*sb);
      p[4]=(float)( sa*cb); p[5]=(float)( sa*sb);
      p[6]=(float)( ca*cb); p[7]=(float)( ca*sb);
    } else {      // U = RY(b)*RX(a)
      double u00r= cb*ca, u00i= sb*sa, u01r=-sb*ca, u01i=-cb*sa;
      double u10r= sb*ca, u10i=-cb*sa, u11r= cb*ca, u11i=-sb*sa;
      p[0]=(float)u00r; p[1]=(float)u00i; p[2]=(float)u01r; p[3]=(float)u01i;
      p[4]=(float)u10r; p[5]=(float)u10i; p[6]=(float)u11r; p[7]=(float)u11i;
      if(q==0){ // M = U^dag Z U: O00, O01 (O11 = -O00)
        double O00 = u00r*u00r+u00i*u00i - (u10r*u10r+u10i*u10i);
        double O01r = u00r*u01r+u00i*u01i - (u10r*u11r+u10i*u11i);
        double O01i = u00r*u01i-u00i*u01r - (u10r*u11i-u10i*u11r);
        gm[368]=(float)O00; gm[369]=(float)O01r; gm[370]=(float)O01i;
      }
    }
  }
}

// passA: window = addr bits {0..3} x {13..21}; bit22 = register butterfly at
// load (q0); partner chunk rows round-trip through per-block ws slot (L2-hot).
__global__ __attribute__((amdgpu_flat_work_group_size(512,512)))
           __attribute__((amdgpu_waves_per_eu(4,4)))
void passA(float* __restrict__ sr, float* __restrict__ si,
           const float* __restrict__ gm, double* __restrict__ accum,
           float2* __restrict__ stash){
  __shared__ float2 lds[TILE];
  int tid = threadIdx.x, b = blockIdx.x;
  int T = ((b&7)<<6) | (b>>3);               // neighbors on same XCD
  int base = (tid<<TILE_BITS) | (T<<4);
  float2* slot = stash + (T<<TILE_BITS);
  C2x2 m0 = ldmat(gm,0,0);                   // qubit 0 = bit 22
  double nrm = 0.0;
  #pragma unroll 1
  for(int h=0;h<2;++h){
    float r0[8],i0[8],r1[8],i1[8];
    ld8(sr+base+8*h, r0); ld8(sr+base+HALF+8*h, r1);
    ld8(si+base+8*h, i0); ld8(si+base+HALF+8*h, i1);
    #pragma unroll
    for(int k=0;k<8;++k)
      nrm += (double)r0[k]*r0[k]+(double)i0[k]*i0[k]
           + (double)r1[k]*r1[k]+(double)i1[k]*i1[k];
    #pragma unroll
    for(int k=0;k<8;++k){
      float y0r = m0.ar*r0[k]-m0.ai*i0[k] + m0.br*r1[k]-m0.bi*i1[k];
      float y0i = m0.ar*i0[k]+m0.ai*r0[k] + m0.br*i1[k]+m0.bi*r1[k];
      float y1r = m0.cr*r0[k]-m0.ci*i0[k] + m0.dr*r1[k]-m0.di*i1[k];
      float y1i = m0.cr*i0[k]+m0.ci*r0[k] + m0.dr*i1[k]+m0.di*r1[k];
      lds[sw((tid<<4)|(8*h+k))] = make_float2(y0r,y0i);
      slot[(8*h+k)*512 + tid]   = make_float2(y1r,y1i);   // chunk1 self-spill
    }
  }
  #pragma unroll
  for(int off=32;off>0;off>>=1) nrm += __shfl_down(nrm, off);
  if((tid&63)==0) atomicAdd(accum+0, nrm);
  __syncthreads();
  #pragma unroll 1
  for(int c=0;c<2;++c){
    if(c==1){
      #pragma unroll
      for(int k=0;k<16;++k) lds[sw((tid<<4)|k)] = slot[k*512 + tid];
      __syncthreads();
    }
    { C2x2 a=ldmat(gm,0,9), b2=ldmat(gm,0,8), c3=ldmat(gm,0,7);
      round3<4,5,6>(lds,a,b2,c3,tid); }   __syncthreads();
    { C2x2 a=ldmat(gm,0,6), b2=ldmat(gm,0,5), c3=ldmat(gm,0,4);
      round3<7,8,9>(lds,a,b2,c3,tid); }   __syncthreads();
    { C2x2 a=ldmat(gm,0,3), b2=ldmat(gm,0,2), c3=ldmat(gm,0,1);
      round3<10,11,12>(lds,a,b2,c3,tid); } __syncthreads();
    {
      float vr[16], vi[16];
      #pragma unroll
      for(int k=0;k<16;++k){ float2 v = lds[sw((tid<<4)|k)]; vr[k]=v.x; vi[k]=v.y; }
      int dst = base + (c ? HALF : 0u);
      st16(sr+dst, vr); st16(si+dst, vi);
    }
    __syncthreads();   // LDS reads done before next chunk's staging
  }
}

// passB: contiguous tiles, output pair (J, J+512). Layer-0 qubits 10..22,
// Gray gather, M-form signed reduce. w tile of chunk0 stashed via ws.
__global__ __attribute__((amdgpu_flat_work_group_size(512,512)))
           __attribute__((amdgpu_waves_per_eu(4,4)))
void passB(const float* __restrict__ sr, const float* __restrict__ si,
           const float* __restrict__ gm, double* __restrict__ accum,
           float2* __restrict__ stash){
  __shared__ float2 lds[TILE];
  int tid = threadIdx.x, J = blockIdx.x;   // 512 blocks
  int gJ = J ^ (J>>1);                     // input tile of chunk0; chunk1 = gJ^768
  int cT = (J&1)<<12;
  int jb16 = ((tid<<4) ^ (tid<<3)) ^ cT;   // Gray gather base (verified r2)
  float4* slot = (float4*)(stash + (J<<TILE_BITS));
  double ss = 0.0;
  #pragma unroll 1
  for(int c=0;c<2;++c){
    int in_base = ((c ? (gJ^768) : gJ) << TILE_BITS) + (tid<<4);
    {
      float vr[16], vi[16];
      ld16(sr+in_base, vr); ld16(si+in_base, vi);
      { C2x2 m=ldmat(gm,0,22);
        #pragma unroll
        for(int k=0;k<16;++k) if(!(k&1)) appair(vr[k],vi[k],vr[k+1],vi[k+1],m); }
      { C2x2 m=ldmat(gm,0,21);
        #pragma unroll
        for(int k=0;k<16;++k) if(!(k&2)) appair(vr[k],vi[k],vr[k+2],vi[k+2],m); }
      { C2x2 m=ldmat(gm,0,20);
        #pragma unroll
        for(int k=0;k<16;++k) if(!(k&4)) appair(vr[k],vi[k],vr[k+4],vi[k+4],m); }
      { C2x2 m=ldmat(gm,0,19);
        #pragma unroll
        for(int k=0;k<8;++k) appair(vr[k],vi[k],vr[k+8],vi[k+8],m); }
      #pragma unroll
      for(int k=0;k<16;++k) lds[sw((tid<<4)|k)] = make_float2(vr[k],vi[k]);
    }
    __syncthreads();
    { C2x2 a=ldmat(gm,0,18), b2=ldmat(gm,0,17), c3=ldmat(gm,0,16);
      round3<4,5,6>(lds,a,b2,c3,tid); }   __syncthreads();
    { C2x2 a=ldmat(gm,0,15), b2=ldmat(gm,0,14), c3=ldmat(gm,0,13);
      round3<7,8,9>(lds,a,b2,c3,tid); }   __syncthreads();
    { C2x2 a=ldmat(gm,0,12), b2=ldmat(gm,0,11), c3=ldmat(gm,0,10);
      round3<10,11,12>(lds,a,b2,c3,tid); } __syncthreads();
    if(c==0){
      #pragma unroll
      for(int g=0;g<8;++g){
        int k0=2*g, k1=2*g+1;
        float2 w0 = lds[sw(jb16 ^ (k0 ^ (k0>>1)))];
        float2 w1 = lds[sw(jb16 ^ (k1 ^ (k1>>1)))];
        slot[g*512 + tid] = make_float4(w0.x,w0.y,w1.x,w1.y);
      }
      __syncthreads();   // gather reads done before chunk1 staging
    } else {
      float a = gm[368], O01r = gm[369], O01i = gm[370];
      #pragma unroll
      for(int g=0;g<8;++g){
        int k0=2*g, k1=2*g+1;
        float2 x0 = lds[sw(jb16 ^ (k0 ^ (k0>>1)))];
        float2 x1 = lds[sw(jb16 ^ (k1 ^ (k1>>1)))];
        float4 w = slot[g*512 + tid];
        // pair (w.xy = tile J side, x = tile J+512 side)
        double p0 = (double)w.x*w.x + (double)w.y*w.y;
        double p1 = (double)x0.x*x0.x + (double)x0.y*x0.y;
        double zr = (double)w.x*x0.x + (double)w.y*x0.y;
        double zi = (double)w.x*x0.y - (double)w.y*x0.x;
        ss += (double)a*(p0-p1) + 2.0*((double)O01r*zr - (double)O01i*zi);
        p0 = (double)w.z*w.z + (double)w.w*w.w;
        p1 = (double)x1.x*x1.x + (double)x1.y*x1.y;
        zr = (double)w.z*x1.x + (double)w.w*x1.y;
        zi = (double)w.z*x1.y - (double)w.w*x1.x;
        ss += (double)a*(p0-p1) + 2.0*((double)O01r*zr - (double)O01i*zi);
      }
    }
  }
  #pragma unroll
  for(int off=32;off>0;off>>=1) ss += __shfl_down(ss, off);
  if((tid&63)==0) atomicAdd(accum+1, ss);
}

__global__ void fink(const double* __restrict__ accum, float* __restrict__ out){
  out[0] = (float)(accum[1]/accum[0]);
}

extern "C" void kernel_launch(void* const* d_in, const int* in_sizes, int n_in,
                              void* d_out, int out_size, void* d_ws, size_t ws_size,
                              hipStream_t stream){
  (void)in_sizes; (void)n_in; (void)out_size; (void)ws_size;
  const float* thetas = (const float*)d_in[0];
  float* sr = (float*)d_in[1];   // mutated in place; harness restores each launch
  float* si = (float*)d_in[2];
  char* ws = (char*)d_ws;
  double* accum = (double*)ws;
  float* gm = (float*)(ws + 64);
  float2* stash = (float2*)(ws + 4096);

  initk<<<1, 64, 0, stream>>>(thetas, gm, accum);
  passA<<<512, THREADS, 0, stream>>>(sr, si, gm, accum, stash);
  passB<<<512, THREADS, 0, stream>>>(sr, si, gm, accum, stash);
  fink<<<1, 1, 0, stream>>>(accum, (float*)d_out);
}

// Round 4
// 170.253 us; speedup vs baseline: 2.4303x; 1.8021x over previous
//
#include <hip/hip_runtime.h>

#define NQ 23
#define HALF (1u<<22)

// ws layout: [0,16) double accum[2]{norm2, signed_sum}; [64,64+1488) float gm.
//
// Math: E = <psi_f|Z_22|psi_f>, psi_f = Lad.L1.Lad.L0.psi.
//  - Final ladder preserves bit22 -> dropped.
//  - L1: only qubit-0 factor survives -> M = U1^dag Z U1 on bit22.
//  - First ladder G: g(x)=x^(x>>1); g(j^2^22)=g(j)^(3<<21) and g preserves
//    bit22, so in pre-G space the observable couples u <-> u^0x600000 only.
//    => E = sum_{u:bit22=0} a(|w|^2-|x|^2) + 2(O01r*zr - O01i*zi),
//       w=phi[u], x=phi[u^(3<<21)], z=conj(w)x, phi = L0.psi.  No gather.
//  pass1: contiguous 8192-amp tiles, layer-0 qubits 10..22 (bits 12..0),
//         norm^2 at load, in-place. 64R+64W.
//  pass2: strided window bits {0..3}u{13..21}, qubits 1..9 in LDS, qubit 0 =
//         bit22 register butterfly, reduce across (bit22, bit21) in-block.
//         64R, no writes.

struct C2x2 { float ar,ai,br,bi,cr,ci,dr,di; };

// LDS swizzle (float2-granular), involution; kept from r3 (conflicts ~0.5%).
__device__ __forceinline__ int sw(int i){ return i ^ (((i>>4)^(i>>8)) & 15); }

__device__ __forceinline__ C2x2 ldmat(const float* __restrict__ gm, int layer, int q){
  const float* p = gm + (layer*NQ + q)*8;
  C2x2 m = {p[0],p[1],p[2],p[3],p[4],p[5],p[6],p[7]};
  return m;
}

__device__ __forceinline__ void appair(float&xr,float&xi,float&yr,float&yi,const C2x2&m){
  float nxr = m.ar*xr - m.ai*xi + m.br*yr - m.bi*yi;
  float nxi = m.ar*xi + m.ai*xr + m.br*yi + m.bi*yr;
  float nyr = m.cr*xr - m.ci*xi + m.dr*yr - m.di*yi;
  float nyi = m.cr*xi + m.ci*xr + m.dr*yi + m.di*yr;
  xr=nxr; xi=nxi; yr=nyr; yi=nyi;
}

__device__ __forceinline__ void ld8(const float* __restrict__ p, float* v){
  const float4* q = (const float4*)p;
  float4 a=q[0], b=q[1];
  v[0]=a.x; v[1]=a.y; v[2]=a.z; v[3]=a.w; v[4]=b.x; v[5]=b.y; v[6]=b.z; v[7]=b.w;
}

template<int B0,int B1,int B2>
__device__ __forceinline__ int depo3(int t){
  int x=t;
  x = ((x & ~((1<<B0)-1))<<1) | (x & ((1<<B0)-1));
  x = ((x & ~((1<<B1)-1))<<1) | (x & ((1<<B1)-1));
  x = ((x & ~((1<<B2)-1))<<1) | (x & ((1<<B2)-1));
  return x;
}

// In-place LDS round: 3 gates on local bits B0<B1<B2; 1024 threads, one
// 8-amp cube per thread. Caller provides barriers.
template<int B0,int B1,int B2>
__device__ __forceinline__ void round3(float2* lds, const C2x2&m0, const C2x2&m1,
                                       const C2x2&m2, int tid){
  int base = depo3<B0,B1,B2>(tid);
  int ad[8];
  float vr[8], vi[8];
  #pragma unroll
  for(int k=0;k<8;++k){
    ad[k] = sw(base | ((k&1)<<B0) | (((k>>1)&1)<<B1) | ((k>>2)<<B2));
    float2 v = lds[ad[k]]; vr[k]=v.x; vi[k]=v.y;
  }
  #pragma unroll
  for(int k=0;k<8;++k) if(!(k&1)) appair(vr[k],vi[k],vr[k+1],vi[k+1],m0);
  #pragma unroll
  for(int k=0;k<8;++k) if(!(k&2)) appair(vr[k],vi[k],vr[k+2],vi[k+2],m1);
  #pragma unroll
  for(int k=0;k<4;++k) appair(vr[k],vi[k],vr[k+4],vi[k+4],m2);
  #pragma unroll
  for(int k=0;k<8;++k) lds[ad[k]] = make_float2(vr[k],vi[k]);
}

__global__ void initk(const float* __restrict__ thetas, float* __restrict__ gm,
                      double* __restrict__ accum){
  int t = threadIdx.x;
  if(t<2) accum[t]=0.0;
  if(t<46){
    int layer = t/NQ, q = t - layer*NQ;
    double a = 0.5*(double)thetas[layer*2*NQ + q*2 + 0];
    double b = 0.5*(double)thetas[layer*2*NQ + q*2 + 1];
    double ca=cos(a), sa=sin(a), cb=cos(b), sb=sin(b);
    float* p = gm + t*8;
    if(layer==0){ // U = RZ(b)*RY(a)
      p[0]=(float)( ca*cb); p[1]=(float)(-ca*sb);
      p[2]=(float)(-sa*cb); p[3]=(float)( sa*sb);
      p[4]=(float)( sa*cb); p[5]=(float)( sa*sb);
      p[6]=(float)( ca*cb); p[7]=(float)( ca*sb);
    } else {      // U = RY(b)*RX(a)
      double u00r= cb*ca, u00i= sb*sa, u01r=-sb*ca, u01i=-cb*sa;
      double u10r= sb*ca, u10i=-cb*sa, u11r= cb*ca, u11i=-sb*sa;
      p[0]=(float)u00r; p[1]=(float)u00i; p[2]=(float)u01r; p[3]=(float)u01i;
      p[4]=(float)u10r; p[5]=(float)u10i; p[6]=(float)u11r; p[7]=(float)u11i;
      if(q==0){ // M = U^dag Z U (verified r3)
        double O00 = u00r*u00r+u00i*u00i - (u10r*u10r+u10i*u10i);
        double O01r = u00r*u01r+u00i*u01i - (u10r*u11r+u10i*u11i);
        double O01i = u00r*u01i-u00i*u01r - (u10r*u11i-u10i*u11r);
        gm[368]=(float)O00; gm[369]=(float)O01r; gm[370]=(float)O01i;
      }
    }
  }
}

// pass1: contiguous tile J (8192 amps). Gates bits 0..2 in regs at load,
// bits 3..11 via 3 LDS rounds, bit 12 fused into the write-back round.
__global__ __attribute__((amdgpu_flat_work_group_size(1024,1024)))
           __attribute__((amdgpu_waves_per_eu(8)))
void pass1(float* __restrict__ sr, float* __restrict__ si,
           const float* __restrict__ gm, double* __restrict__ accum){
  __shared__ float2 lds[8192];
  int tid = threadIdx.x, J = blockIdx.x;
  int base = (J<<13) | (tid<<3);
  float vr[8], vi[8];
  ld8(sr+base, vr); ld8(si+base, vi);
  float nrm = 0.f;
  #pragma unroll
  for(int k=0;k<8;++k) nrm += vr[k]*vr[k] + vi[k]*vi[k];
  { C2x2 m = ldmat(gm,0,22);
    #pragma unroll
    for(int k=0;k<8;++k) if(!(k&1)) appair(vr[k],vi[k],vr[k+1],vi[k+1],m); }
  { C2x2 m = ldmat(gm,0,21);
    #pragma unroll
    for(int k=0;k<8;++k) if(!(k&2)) appair(vr[k],vi[k],vr[k+2],vi[k+2],m); }
  { C2x2 m = ldmat(gm,0,20);
    #pragma unroll
    for(int k=0;k<4;++k) appair(vr[k],vi[k],vr[k+4],vi[k+4],m); }
  #pragma unroll
  for(int k=0;k<8;++k) lds[sw((tid<<3)|k)] = make_float2(vr[k],vi[k]);
  __syncthreads();
  { C2x2 a=ldmat(gm,0,19),b=ldmat(gm,0,18),c=ldmat(gm,0,17);
    round3<3,4,5>(lds,a,b,c,tid); }  __syncthreads();
  { C2x2 a=ldmat(gm,0,16),b=ldmat(gm,0,15),c=ldmat(gm,0,14);
    round3<6,7,8>(lds,a,b,c,tid); }  __syncthreads();
  { C2x2 a=ldmat(gm,0,13),b=ldmat(gm,0,12),c=ldmat(gm,0,11);
    round3<9,10,11>(lds,a,b,c,tid); } __syncthreads();
  { // write-back round: cube {0,1,12}, gate bit12 = qubit 10
    int b2 = tid<<2;                  // bits 2..11 = tid
    float wr[8], wi[8];
    #pragma unroll
    for(int k=0;k<8;++k){
      float2 v = lds[sw(b2 | (k&3) | ((k>>2)<<12))];
      wr[k]=v.x; wi[k]=v.y;
    }
    C2x2 m = ldmat(gm,0,10);
    #pragma unroll
    for(int k=0;k<4;++k) appair(wr[k],wi[k],wr[k+4],wi[k+4],m);
    int g0 = (J<<13) | b2;
    *(float4*)(sr+g0)      = make_float4(wr[0],wr[1],wr[2],wr[3]);
    *(float4*)(si+g0)      = make_float4(wi[0],wi[1],wi[2],wi[3]);
    *(float4*)(sr+g0+4096) = make_float4(wr[4],wr[5],wr[6],wr[7]);
    *(float4*)(si+g0+4096) = make_float4(wi[4],wi[5],wi[6],wi[7]);
  }
  // block reduction of nrm via now-dead LDS
  double d = (double)nrm;
  #pragma unroll
  for(int off=32;off>0;off>>=1) d += __shfl_down(d, off);
  __syncthreads();
  double* red = (double*)lds;
  if((tid&63)==0) red[tid>>6] = d;
  __syncthreads();
  if(tid==0){
    double s=0;
    #pragma unroll
    for(int i=0;i<16;++i) s += red[i];
    atomicAdd(accum+0, s);
  }
}

// pass2: strided window {0..3}u{13..21}; T = bits 4..12 (512 blocks);
// bit22 = register butterfly (qubit 0); qubits 1..9 via LDS rounds on each
// bit22-half; reduce pairs (bit22, local bit12=bit21) with no global writes.
__global__ __attribute__((amdgpu_flat_work_group_size(1024,1024)))
           __attribute__((amdgpu_waves_per_eu(8)))
void pass2(const float* __restrict__ sr, const float* __restrict__ si,
           const float* __restrict__ gm, double* __restrict__ accum){
  __shared__ float2 lds[8192];
  int tid = threadIdx.x, b = blockIdx.x;
  int T = ((b&7)<<6) | (b>>3);        // T,T^1 = same XCD (b, b+8)
  int ga = ((tid>>1)<<13) | (T<<4) | ((tid&1)<<3);
  float r0[8], i0[8], r1[8], i1[8];
  ld8(sr+ga, r0);      ld8(si+ga, i0);
  ld8(sr+ga+HALF, r1); ld8(si+ga+HALF, i1);
  { C2x2 m = ldmat(gm,0,0);           // qubit 0 butterfly on bit22
    #pragma unroll
    for(int k=0;k<8;++k){
      float y0r = m.ar*r0[k]-m.ai*i0[k] + m.br*r1[k]-m.bi*i1[k];
      float y0i = m.ar*i0[k]+m.ai*r0[k] + m.br*i1[k]+m.bi*r1[k];
      float y1r = m.cr*r0[k]-m.ci*i0[k] + m.dr*r1[k]-m.di*i1[k];
      float y1i = m.cr*i0[k]+m.ci*r0[k] + m.dr*i1[k]+m.di*r1[k];
      r0[k]=y0r; i0[k]=y0i; r1[k]=y1r; i1[k]=y1i;
    } }
  int lb = tid<<3;
  #pragma unroll
  for(int k=0;k<8;++k) lds[sw(lb|k)] = make_float2(r0[k],i0[k]);
  __syncthreads();
  // local bits 4..12 = global 13..21 = qubits 9..1
  { C2x2 a=ldmat(gm,0,9),b2=ldmat(gm,0,8),c=ldmat(gm,0,7);
    round3<4,5,6>(lds,a,b2,c,tid); }   __syncthreads();
  { C2x2 a=ldmat(gm,0,6),b2=ldmat(gm,0,5),c=ldmat(gm,0,4);
    round3<7,8,9>(lds,a,b2,c,tid); }   __syncthreads();
  { C2x2 a=ldmat(gm,0,3),b2=ldmat(gm,0,2),c=ldmat(gm,0,1);
    round3<10,11,12>(lds,a,b2,c,tid); } __syncthreads();
  float wr[8], wi[8];
  #pragma unroll
  for(int k=0;k<8;++k){ float2 v = lds[sw(lb|k)]; wr[k]=v.x; wi[k]=v.y; }
  __syncthreads();
  #pragma unroll
  for(int k=0;k<8;++k) lds[sw(lb|k)] = make_float2(r1[k],i1[k]);
  __syncthreads();
  { C2x2 a=ldmat(gm,0,9),b2=ldmat(gm,0,8),c=ldmat(gm,0,7);
    round3<4,5,6>(lds,a,b2,c,tid); }   __syncthreads();
  { C2x2 a=ldmat(gm,0,6),b2=ldmat(gm,0,5),c=ldmat(gm,0,4);
    round3<7,8,9>(lds,a,b2,c,tid); }   __syncthreads();
  { C2x2 a=ldmat(gm,0,3),b2=ldmat(gm,0,2),c=ldmat(gm,0,1);
    round3<10,11,12>(lds,a,b2,c,tid); } __syncthreads();
  float a = gm[368], O1r = gm[369], O1i = gm[370];
  float ss = 0.f;
  #pragma unroll
  for(int k=0;k<8;++k){                // partner: bit22 flip + bit21 flip
    float2 v = lds[sw((lb|k)^0x1000)];
    float xr=v.x, xi=v.y;
    float p0 = wr[k]*wr[k]+wi[k]*wi[k];
    float p1 = xr*xr+xi*xi;
    float zr = wr[k]*xr + wi[k]*xi;
    float zi = wr[k]*xi - wi[k]*xr;
    ss += a*(p0-p1) + 2.f*(O1r*zr - O1i*zi);
  }
  double d = (double)ss;
  #pragma unroll
  for(int off=32;off>0;off>>=1) d += __shfl_down(d, off);
  __syncthreads();                      // x-reads done before LDS reuse
  double* red = (double*)lds;
  if((tid&63)==0) red[tid>>6] = d;
  __syncthreads();
  if(tid==0){
    double s=0;
    #pragma unroll
    for(int i=0;i<16;++i) s += red[i];
    atomicAdd(accum+1, s);
  }
}

__global__ void fink(const double* __restrict__ accum, float* __restrict__ out){
  out[0] = (float)(accum[1]/accum[0]);
}

extern "C" void kernel_launch(void* const* d_in, const int* in_sizes, int n_in,
                              void* d_out, int out_size, void* d_ws, size_t ws_size,
                              hipStream_t stream){
  (void)in_sizes; (void)n_in; (void)out_size; (void)ws_size;
  const float* thetas = (const float*)d_in[0];
  float* sr = (float*)d_in[1];   // mutated in place; harness restores each launch
  float* si = (float*)d_in[2];
  char* ws = (char*)d_ws;
  double* accum = (double*)ws;
  float* gm = (float*)(ws + 64);

  initk<<<1, 64, 0, stream>>>(thetas, gm, accum);
  pass1<<<1024, 1024, 0, stream>>>(sr, si, gm, accum);
  pass2<<<512, 1024, 0, stream>>>(sr, si, gm, accum);
  fink<<<1, 1, 0, stream>>>(accum, (float*)d_out);
}

// Round 5
// 119.966 us; speedup vs baseline: 3.4490x; 1.4192x over previous
//
#include <hip/hip_runtime.h>

#define Q21 (1u<<21)
#define THREADS 512
#define BLOCKS 1024   // 1024*512 threads * 4 quads = 2^21 quads

// ws layout: [0,16) double accum[2]{norm2, signed_sum}; [64,64+64) float cmat[16].
//
// Math chain (each step verified on HW in r1-r4, absmax 0 at every stage):
//  E = <psi_f|Z_22|psi_f>/||psi||^2, psi_f = Lad.L1.Lad.L0.psi.
//  1. Final ladder preserves bit22 -> dropped.                    [r2]
//  2. L1: only qubit-0 survives -> M = U1_0^dag Z U1_0 on bit22.  [r3]
//  3. First ladder g(x)=x^(x>>1): g(x^2^22)=g(x)^(3<<21), g keeps bit22
//     -> observable B on bits {22,21}: diag(+a,+a,-a,-a),
//        B[0][3]=B[1][2]=O01 (+h.c.).                             [r4]
//  4. NEW: B acts only on bits {22,21}; every L0 factor outside those bits
//     commutes with B(x)I and cancels. Survivors: U0_0 (bit22), U0_1 (bit21).
//     C = (U0_0 (x) U0_1)^dag B (U0_0 (x) U0_1)  -- fixed 4x4 Hermitian.
//  => E = sum_v q(v)^dag C q(v) / sum |psi|^2,
//     q(v) = (psi[v], psi[v+2^21], psi[v+2^22], psi[v+3*2^21]), v < 2^21.
// Single read-only streaming pass; 64 MB read, 0 write.

struct cd { double r, i; };
__device__ __forceinline__ cd cmul(cd a, cd b){ return {a.r*b.r - a.i*b.i, a.r*b.i + a.i*b.r}; }
__device__ __forceinline__ cd cjg(cd a){ return {a.r, -a.i}; }
__device__ __forceinline__ cd cadd(cd a, cd b){ return {a.r+b.r, a.i+b.i}; }

__global__ void initk(const float* __restrict__ thetas, float* __restrict__ cmat,
                      double* __restrict__ accum){
  if(threadIdx.x != 0) return;
  accum[0]=0.0; accum[1]=0.0;
  // thetas layout: idx = layer*46 + q*2 + r. Layer0: RY(t0) then RZ(t1);
  // layer1: RX then RY.
  double a0=0.5*(double)thetas[0], b0=0.5*(double)thetas[1];   // qubit0 L0
  double a1=0.5*(double)thetas[2], b1=0.5*(double)thetas[3];   // qubit1 L0
  double ax=0.5*(double)thetas[46], bx=0.5*(double)thetas[47]; // qubit0 L1
  // U = RZ(b)*RY(a):
  //   [ ca e^{-ib}  -sa e^{-ib} ; sa e^{ib}  ca e^{ib} ]
  cd U0[2][2], U1[2][2];
  {
    double ca=cos(a0), sa=sin(a0), cb=cos(b0), sb=sin(b0);
    U0[0][0]={ca*cb,-ca*sb}; U0[0][1]={-sa*cb, sa*sb};
    U0[1][0]={sa*cb, sa*sb}; U0[1][1]={ ca*cb, ca*sb};
  }
  {
    double ca=cos(a1), sa=sin(a1), cb=cos(b1), sb=sin(b1);
    U1[0][0]={ca*cb,-ca*sb}; U1[0][1]={-sa*cb, sa*sb};
    U1[1][0]={sa*cb, sa*sb}; U1[1][1]={ ca*cb, ca*sb};
  }
  // V = RY(bx)*RX(ax)  (layer1 qubit0)
  cd V[2][2];
  {
    double ca=cos(ax), sa=sin(ax), cb=cos(bx), sb=sin(bx);
    V[0][0]={cb*ca, sb*sa}; V[0][1]={-sb*ca,-cb*sa};
    V[1][0]={sb*ca,-cb*sa}; V[1][1]={ cb*ca,-sb*sa};
  }
  // M = V^dag Z V on bit22: aM = |V00|^2-|V10|^2, O01 = conj(V00)V01 - conj(V10)V11
  double aM = (V[0][0].r*V[0][0].r+V[0][0].i*V[0][0].i)
            - (V[1][0].r*V[1][0].r+V[1][0].i*V[1][0].i);
  cd O01 = cadd(cmul(cjg(V[0][0]),V[0][1]), {-cmul(cjg(V[1][0]),V[1][1]).r,
                                             -cmul(cjg(V[1][0]),V[1][1]).i});
  // B on m=(bit22<<1)|bit21
  cd B[4][4];
  for(int j=0;j<4;++j) for(int k=0;k<4;++k) B[j][k]={0,0};
  B[0][0]={aM,0}; B[1][1]={aM,0}; B[2][2]={-aM,0}; B[3][3]={-aM,0};
  B[0][3]=O01; B[3][0]=cjg(O01); B[1][2]=O01; B[2][1]=cjg(O01);
  // W = kron(U0, U1);  C = W^dag B W
  cd W[4][4];
  for(int m=0;m<4;++m) for(int n=0;n<4;++n)
    W[m][n] = cmul(U0[m>>1][n>>1], U1[m&1][n&1]);
  cd C[4][4];
  for(int m=0;m<4;++m) for(int n=0;n<4;++n){
    cd s={0,0};
    for(int j=0;j<4;++j) for(int k=0;k<4;++k)
      s = cadd(s, cmul(cmul(cjg(W[j][m]), B[j][k]), W[k][n]));
    C[m][n]=s;
  }
  cmat[0]=(float)C[0][0].r; cmat[1]=(float)C[1][1].r;
  cmat[2]=(float)C[2][2].r; cmat[3]=(float)C[3][3].r;
  const int pm[6]={0,0,0,1,1,2}, pn[6]={1,2,3,2,3,3};
  for(int p=0;p<6;++p){
    cmat[4+2*p]   = (float)(2.0*C[pm[p]][pn[p]].r);
    cmat[5+2*p]   = (float)(2.0*C[pm[p]][pn[p]].i);
  }
}

// Streaming quad-form reduce: one float4 per stream per thread, 8 streams.
__global__ __launch_bounds__(THREADS)
void mainp(const float* __restrict__ sr, const float* __restrict__ si,
           const float* __restrict__ cmat, double* __restrict__ accum){
  int gt = blockIdx.x*THREADS + threadIdx.x;
  int v  = gt<<2;
  float rr[4][4], ii[4][4];
  *(float4*)&rr[0][0] = *(const float4*)(sr+v);
  *(float4*)&rr[1][0] = *(const float4*)(sr+v+Q21);
  *(float4*)&rr[2][0] = *(const float4*)(sr+v+2*Q21);
  *(float4*)&rr[3][0] = *(const float4*)(sr+v+3*Q21);
  *(float4*)&ii[0][0] = *(const float4*)(si+v);
  *(float4*)&ii[1][0] = *(const float4*)(si+v+Q21);
  *(float4*)&ii[2][0] = *(const float4*)(si+v+2*Q21);
  *(float4*)&ii[3][0] = *(const float4*)(si+v+3*Q21);
  float cm[16];
  #pragma unroll
  for(int k=0;k<16;++k) cm[k]=cmat[k];      // wave-uniform -> scalar loads
  float ssum=0.f, nsum=0.f;
  #pragma unroll
  for(int e=0;e<4;++e){
    float qr[4]={rr[0][e],rr[1][e],rr[2][e],rr[3][e]};
    float qi[4]={ii[0][e],ii[1][e],ii[2][e],ii[3][e]};
    float n0=qr[0]*qr[0]+qi[0]*qi[0], n1=qr[1]*qr[1]+qi[1]*qi[1];
    float n2=qr[2]*qr[2]+qi[2]*qi[2], n3=qr[3]*qr[3]+qi[3]*qi[3];
    nsum += (n0+n1)+(n2+n3);
    float s = cm[0]*n0 + cm[1]*n1 + cm[2]*n2 + cm[3]*n3;
    const int pm[6]={0,0,0,1,1,2}, pn[6]={1,2,3,2,3,3};
    #pragma unroll
    for(int p=0;p<6;++p){
      int m=pm[p], n=pn[p];
      float zr = qr[m]*qr[n] + qi[m]*qi[n];
      float zi = qr[m]*qi[n] - qi[m]*qr[n];
      s += cm[4+2*p]*zr - cm[5+2*p]*zi;
    }
    ssum += s;
  }
  double ds=(double)ssum, dn=(double)nsum;
  #pragma unroll
  for(int off=32;off>0;off>>=1){ ds += __shfl_down(ds,off); dn += __shfl_down(dn,off); }
  __shared__ double red[16];
  int w = threadIdx.x>>6;
  if((threadIdx.x&63)==0){ red[w]=ds; red[8+w]=dn; }
  __syncthreads();
  if(threadIdx.x==0){
    double s=0,n=0;
    #pragma unroll
    for(int i=0;i<8;++i){ s+=red[i]; n+=red[8+i]; }
    atomicAdd(accum+1, s); atomicAdd(accum+0, n);
  }
}

__global__ void fink(const double* __restrict__ accum, float* __restrict__ out){
  out[0] = (float)(accum[1]/accum[0]);
}

extern "C" void kernel_launch(void* const* d_in, const int* in_sizes, int n_in,
                              void* d_out, int out_size, void* d_ws, size_t ws_size,
                              hipStream_t stream){
  (void)in_sizes; (void)n_in; (void)out_size; (void)ws_size;
  const float* thetas = (const float*)d_in[0];
  const float* sr = (const float*)d_in[1];
  const float* si = (const float*)d_in[2];
  char* ws = (char*)d_ws;
  double* accum = (double*)ws;
  float* cmat = (float*)(ws + 64);

  initk<<<1, 64, 0, stream>>>(thetas, cmat, accum);
  mainp<<<BLOCKS, THREADS, 0, stream>>>(sr, si, cmat, accum);
  fink<<<1, 1, 0, stream>>>(accum, (float*)d_out);
}